// Round 6
// baseline (249.791 us; speedup 1.0000x reference)
//
#include <hip/hip_runtime.h>

// MultiQueryAttention: B=2, S=2048, E=1024, H=16, D=64. fp32 I/O.
#define E_DIM  1024
#define H_HEADS 16
#define D_HEAD  64
#define B_BATCH 2
#define S_SEQ  2048
#define M_ROWS (B_BATCH * S_SEQ)   // 4096

typedef unsigned short u16;
typedef unsigned int   u32;
typedef __attribute__((ext_vector_type(8))) short bf16x8;
typedef __attribute__((ext_vector_type(4))) short bf16x4;
typedef __attribute__((ext_vector_type(4))) float f32x4;

#define MFMA32(a, b, c) __builtin_amdgcn_mfma_f32_16x16x32_bf16(a, b, c, 0, 0, 0)

#if __has_builtin(__builtin_amdgcn_mfma_f32_16x16x16bf16_1k)
#define HAVE_MFMA16 1
#define MFMA16(a, b, c) __builtin_amdgcn_mfma_f32_16x16x16bf16_1k(a, b, c, 0, 0, 0)
#else
#define HAVE_MFMA16 0
#endif

__device__ __forceinline__ u16 f2bf(float f) {
    union { float f; u32 i; } x; x.f = f;
    u32 r = x.i + 0x7fffu + ((x.i >> 16) & 1u);   // RNE (finite inputs)
    return (u16)(r >> 16);
}

#if __has_builtin(__builtin_amdgcn_cvt_pk_bf16_f32)
typedef __attribute__((ext_vector_type(2))) __bf16 bfp2;
__device__ __forceinline__ u32 pk2(float a, float b) {
    bfp2 t = __builtin_amdgcn_cvt_pk_bf16_f32(a, b);
    union { bfp2 v; u32 u; } c; c.v = t; return c.u;
}
#else
__device__ __forceinline__ u32 pk2(float a, float b) {
    return (u32)f2bf(a) | ((u32)f2bf(b) << 16);
}
#endif

__device__ __forceinline__ bf16x8 cvt8(const float4& a, const float4& b) {
    union { u32 u[4]; bf16x8 v; } t;
    t.u[0] = pk2(a.x, a.y); t.u[1] = pk2(a.z, a.w);
    t.u[2] = pk2(b.x, b.y); t.u[3] = pk2(b.z, b.w);
    return t.v;
}
__device__ __forceinline__ bf16x4 pack4(const f32x4& v) {
    union { u32 u[2]; bf16x4 w; } t;
    t.u[0] = pk2(v[0], v[1]); t.u[1] = pk2(v[2], v[3]);
    return t.w;
}

// async global->LDS, 16B/lane. LDS dest must be wave-uniform base + lane*16.
__device__ __forceinline__ void gl_lds16(const u16* g, u16* l) {
    __builtin_amdgcn_global_load_lds(
        (const __attribute__((address_space(1))) u32*)g,
        (__attribute__((address_space(3))) u32*)l, 16, 0, 0);
}

// ---------------------------------------------------------------------------
// Fused prep: K/V projection (128 blocks, FIRST so they start earliest) +
// fp32->bf16 casts of query/Wq/Wo (3072 blocks).
// kv_proj this round: double-buffered single-barrier loop with loads issued
// one compute-phase early (T14): load(t+1) -> barrier -> compute(t) ->
// cvt+write(t+1). HBM latency hides under compute; one barrier per K-step.
// ---------------------------------------------------------------------------
__global__ __launch_bounds__(256) void prep_kernel(
    const float* __restrict__ query, const float* __restrict__ Wq,
    const float* __restrict__ Wo,
    u16* __restrict__ qc, u16* __restrict__ wq_bf, u16* __restrict__ wo_bf,
    const float* __restrict__ key, const float* __restrict__ value,
    const float* __restrict__ Wk, const float* __restrict__ Wv,
    const float* __restrict__ bk, const float* __restrict__ bv,
    u16* __restrict__ Kout, u16* __restrict__ VTout, int M, int K)
{
    __shared__ u16 Asm[2][64 * 32];
    __shared__ u16 Bsm[2][64 * 32];

    const int bid = blockIdx.x;
    const int tid = threadIdx.x;

    if (bid >= 128) {
        // ---- cast branch: 3072 blocks, 2048 elems each
        const int cbid = bid - 128;
        const float* src; u16* dst; size_t base;
        if (cbid < 2048)      { src = query; dst = qc;    base = (size_t)cbid * 2048; }
        else if (cbid < 2560) { src = Wq;    dst = wq_bf; base = (size_t)(cbid - 2048) * 2048; }
        else                  { src = Wo;    dst = wo_bf; base = (size_t)(cbid - 2560) * 2048; }
        const size_t i = base + (size_t)tid * 8;
        float4 a = ((const float4*)(src + i))[0];
        float4 b = ((const float4*)(src + i))[1];
        *(bf16x8*)(dst + i) = cvt8(a, b);
        return;
    }

    // ---- kv_proj branch: blocks 0..127 (64 m-tiles x {K,V})
    const bool vproj = (bid >= 64);
    const float* A    = vproj ? value : key;
    const float* W    = vproj ? Wv : Wk;
    const float* bias = vproj ? bv : bk;

    const int w  = tid >> 6;
    const int ln = tid & 63;
    const int n  = ln & 15;
    const int qd = ln >> 4;
    const int wm = (w & 1) * 32;
    const int wn = (w >> 1) * 32;
    const int m0 = (bid & 63) * 64;

    const int srow = tid >> 2;
    const int scol = (tid & 3) * 8;

    f32x4 acc[2][2];
#pragma unroll
    for (int mt = 0; mt < 2; mt++)
#pragma unroll
        for (int nt = 0; nt < 2; nt++) acc[mt][nt] = (f32x4){0.f, 0.f, 0.f, 0.f};

    float4 a0, a1, w0, w1;
    auto loadT = [&](int k0) {
        const float* pa = A + (size_t)(m0 + srow) * K + k0 + scol;
        const float* pw = W + (size_t)srow * K + k0 + scol;
        a0 = ((const float4*)pa)[0]; a1 = ((const float4*)pa)[1];
        w0 = ((const float4*)pw)[0]; w1 = ((const float4*)pw)[1];
    };

    const int nk = K / 32;                 // 32 K-steps
    loadT(0);
    *(bf16x8*)&Asm[0][srow * 32 + scol] = cvt8(a0, a1);
    *(bf16x8*)&Bsm[0][srow * 32 + scol] = cvt8(w0, w1);

    for (int t = 0; t < nk; ++t) {
        if (t + 1 < nk) loadT((t + 1) * 32);   // global loads in flight
        __syncthreads();                        // buf[t&1] writes visible

        bf16x8 af[2], bfr[2];
#pragma unroll
        for (int t2 = 0; t2 < 2; t2++) {
            af[t2]  = *(const bf16x8*)&Asm[t & 1][(wm + t2 * 16 + n) * 32 + qd * 8];
            bfr[t2] = *(const bf16x8*)&Bsm[t & 1][(wn + t2 * 16 + n) * 32 + qd * 8];
        }
#pragma unroll
        for (int mt = 0; mt < 2; mt++)
#pragma unroll
            for (int nt = 0; nt < 2; nt++)
                acc[mt][nt] = MFMA32(af[mt], bfr[nt], acc[mt][nt]);

        if (t + 1 < nk) {
            *(bf16x8*)&Asm[(t + 1) & 1][srow * 32 + scol] = cvt8(a0, a1);
            *(bf16x8*)&Bsm[(t + 1) & 1][srow * 32 + scol] = cvt8(w0, w1);
        }
    }

    if (!vproj) {
#pragma unroll
        for (int mt = 0; mt < 2; mt++)
#pragma unroll
            for (int r = 0; r < 4; r++) {
                const int row = m0 + wm + mt * 16 + qd * 4 + r;
#pragma unroll
                for (int nt = 0; nt < 2; nt++) {
                    const int col = wn + nt * 16 + n;
                    Kout[(size_t)row * 64 + col] = f2bf(acc[mt][nt][r] + bias[col]);
                }
            }
    } else {
#pragma unroll
        for (int mt = 0; mt < 2; mt++)
#pragma unroll
            for (int nt = 0; nt < 2; nt++) {
                const int col = wn + nt * 16 + n;
                const int row0 = m0 + wm + mt * 16 + qd * 4;
                float b4 = bias[col];
                ushort4 pk;
                pk.x = f2bf(acc[mt][nt][0] + b4);
                pk.y = f2bf(acc[mt][nt][1] + b4);
                pk.z = f2bf(acc[mt][nt][2] + b4);
                pk.w = f2bf(acc[mt][nt][3] + b4);
                *(ushort4*)&VTout[(size_t)col * M + row0] = pk;
            }
    }
}

// ---------------------------------------------------------------------------
// MFMA GEMM: C = (A @ W^T) * scale + bias*scale.  A,W bf16 [.,K] row-major.
// Tile 128(M) x 64(N), BK=64, 256 threads = 4 waves (2M x 2N, wave 64x32).
// THIS ROUND (T3+T4): 3-buffer LDS rotation, 2-deep prefetch, counted
// s_waitcnt vmcnt(6) + raw s_barrier per K-step -- the staging queue is never
// drained to 0 in the main loop (the __syncthreads drain was the stall; m218:
// counted-vs-drain0 = +38..73%).
//   Schedule per iter t: WAIT vmcnt(6) [tile t's 6 loads done, t+1's in
//   flight] -> s_barrier [all waves waited -> buf t complete; all waves
//   finished compute(t-1), last reader of buf (t+2)%3] -> stage(t+2) ->
//   compute(t). Epilogue peels t=nt-2 (vmcnt 6) and t=nt-1 (vmcnt 0).
//   6 = gl_lds16 per thread per stage (4 A + 2 B), uniform.
// Bias/C traffic sits after the final vmcnt(0) so loop counts stay exact.
// LDS 72 KB -> 2 blocks/CU. Grid (N/64, M/128) = 512 blocks.
// 3-bit XOR chunk swizzle: stored slot s of row r holds global chunk
// s ^ (r&3) ^ ((r>>2)&3); frag reads use slot qd ^ (n&3) ^ (n>>2) -> <=2-way
// conflicts (free, m136). Frag layouts per m89/m101.
// ---------------------------------------------------------------------------
template<bool OUT_BF16>
__global__ __launch_bounds__(256, 2) void gemm_bf16_kernel(
    const u16* __restrict__ A, const u16* __restrict__ W,
    const float* __restrict__ bias, void* __restrict__ Cv,
    int M, int N, int K, float scale)
{
    __shared__ u16 Asm[3][2][128 * 32];   // [buf][k-half][row*32+c]  48 KB
    __shared__ u16 Bsm[3][2][64 * 32];    //                          24 KB

    const int tid = threadIdx.x;          // 0..255
    const int w  = tid >> 6;              // 0..3
    const int ln = tid & 63;
    const int n  = ln & 15;
    const int qd = ln >> 4;
    const int ns = (n & 3) ^ (n >> 2);    // read-side swizzle term
    const int wm = (w & 1) * 64;          // wave M offset (2 waves in M)
    const int wn = (w >> 1) * 32;         // wave N offset (2 waves in N)

    const int m0 = blockIdx.y * 128;
    const int n0 = blockIdx.x * 64;

    // staging: 256 chunks of 8 elems cover a [64][32] half-tile per call
    const int srow = tid >> 2;            // 0..63
    const int sblk = tid & 3;             // dest chunk slot
    const int sc   = ((sblk ^ (srow & 3) ^ ((srow >> 2) & 3)) * 8);  // swizzled source col

    f32x4 acc[4][2];
#pragma unroll
    for (int mt = 0; mt < 4; mt++)
#pragma unroll
        for (int nt = 0; nt < 2; nt++) acc[mt][nt] = (f32x4){0.f, 0.f, 0.f, 0.f};

    auto stage = [&](int p, int k0) {     // 6 gl_lds16 per thread, uniform
#pragma unroll
        for (int kb = 0; kb < 2; kb++)
#pragma unroll
            for (int g = 0; g < 2; g++) {
                const int row = g * 64 + srow;   // row&3==srow&3, (row>>2)&3==(srow>>2)&3
                gl_lds16(A + (size_t)(m0 + row) * K + k0 + kb * 32 + sc,
                         &Asm[p][kb][row * 32 + sblk * 8]);
            }
#pragma unroll
        for (int kb = 0; kb < 2; kb++)
            gl_lds16(W + (size_t)(n0 + srow) * K + k0 + kb * 32 + sc,
                     &Bsm[p][kb][srow * 32 + sblk * 8]);
    };
    auto compute = [&](int p) {
        bf16x8 af[4][2], bfr[2][2];
#pragma unroll
        for (int kb = 0; kb < 2; kb++) {
#pragma unroll
            for (int mt = 0; mt < 4; mt++) {
                const int r = wm + mt * 16 + n;   // (r>>2)&3 == (n>>2)&3
                af[mt][kb] = *(const bf16x8*)&Asm[p][kb][r * 32 + ((qd ^ ns) * 8)];
            }
#pragma unroll
            for (int nt = 0; nt < 2; nt++) {
                const int r = wn + nt * 16 + n;
                bfr[nt][kb] = *(const bf16x8*)&Bsm[p][kb][r * 32 + ((qd ^ ns) * 8)];
            }
        }
#pragma unroll
        for (int kb = 0; kb < 2; kb++)
#pragma unroll
            for (int mt = 0; mt < 4; mt++)
#pragma unroll
                for (int nt = 0; nt < 2; nt++)
                    acc[mt][nt] = MFMA32(af[mt][kb], bfr[nt][kb], acc[mt][nt]);
    };

    const int nt_tiles = K / 64;          // 16
    // prologue: tiles 0,1 in flight (12 loads/thread)
    stage(0, 0);
    stage(1, 64);

    int pc = 0, ps = 2;                   // t%3, (t+2)%3
    for (int t = 0; t + 2 < nt_tiles; ++t) {
        asm volatile("s_waitcnt vmcnt(6)" ::: "memory");   // tile t landed
        __builtin_amdgcn_s_barrier();                      // all waves waited
        __builtin_amdgcn_sched_barrier(0);
        stage(ps, (t + 2) * 64);                           // 2-deep prefetch
        compute(pc);
        pc = (pc == 2) ? 0 : pc + 1;
        ps = (ps == 2) ? 0 : ps + 1;
    }
    // t = nt-2: tile nt-1 still in flight
    asm volatile("s_waitcnt vmcnt(6)" ::: "memory");
    __builtin_amdgcn_s_barrier();
    __builtin_amdgcn_sched_barrier(0);
    compute(pc);
    pc = (pc == 2) ? 0 : pc + 1;
    // t = nt-1: final drain
    asm volatile("s_waitcnt vmcnt(0)" ::: "memory");
    __builtin_amdgcn_s_barrier();
    __builtin_amdgcn_sched_barrier(0);
    compute(pc);

    float bb[2];
#pragma unroll
    for (int nt = 0; nt < 2; nt++) bb[nt] = bias[n0 + wn + nt * 16 + n] * scale;

#pragma unroll
    for (int mt = 0; mt < 4; mt++)
#pragma unroll
        for (int r = 0; r < 4; r++) {
            const int row = m0 + wm + mt * 16 + qd * 4 + r;
#pragma unroll
            for (int nt = 0; nt < 2; nt++) {
                const int col = n0 + wn + nt * 16 + n;
                float v = acc[mt][nt][r] * scale + bb[nt];
                if (OUT_BF16) ((u16*)Cv)[(size_t)row * N + col] = f2bf(v);
                else        ((float*)Cv)[(size_t)row * N + col] = v;
            }
        }
}

// ---------------------------------------------------------------------------
// MFMA flash MQA attention — frozen from round 5 (79 us; VALU+MFMA ~82%
// combined -> near issue-bound; next attn lever is work removal, not overlap).
// Double-buffered K/V, single barrier per s-tile; 3-bit XOR swizzle.
//  * S^T = K Q^T; P exits in A-frag orientation -> PV via MFMA16 (registers).
//  * Max-free exp2 softmax (scores bounded), lsum reduced in epilogue.
// Q: [M,E] bf16 pre-scaled; K: [M,64] bf16; VT: [64,M] bf16.
// O aliases Q (block reads exactly the region it writes).
// ---------------------------------------------------------------------------
__global__ __launch_bounds__(256, 2) void mqa_attn_mfma_kernel(
    const u16* Q, const u16* __restrict__ K,
    const u16* __restrict__ VT, u16* O)
{
    __shared__ u16 ksm[2][2][128 * 32];   // [buf][k-half][row][32]  32 KB
    __shared__ u16 vsm[2][4][64 * 32];    // [buf][s-chunk32][d][32] 32 KB
#if !HAVE_MFMA16
    __shared__ u16 psm[4][32 * 128];
#endif

    const int tid = threadIdx.x;
    const int w   = tid >> 6;
    const int ln  = tid & 63;
    const int n   = ln & 15;
    const int qd  = ln >> 4;
    const int lr  = ln >> 2;           // 0..15
    const int blk = ln & 3;
    const int ns  = (n & 3) ^ (n >> 2);        // read-side swizzle term
    const int rs  = (lr & 3) ^ (lr >> 2);      // stage-side swizzle term

    const int bid = blockIdx.x;
    const int qb = bid & 15;
    const int h  = (bid >> 4) & (H_HEADS - 1);
    const int b  = bid >> 8;
    const int q0 = qb * 128;

    const u16* kg = K  + (size_t)b * S_SEQ * 64;
    const u16* vg = VT + (size_t)b * S_SEQ;

    auto stageKV = [&](int p, int s0) {
#pragma unroll
        for (int kb = 0; kb < 2; kb++)
#pragma unroll
            for (int j = 0; j < 2; j++) {
                int row = w * 32 + j * 16 + lr;   // row&3==lr&3, (row>>2)&3==lr>>2
                gl_lds16(kg + (size_t)(s0 + row) * 64 + kb * 32 + ((blk ^ rs) * 8),
                         &ksm[p][kb][row * 32 + blk * 8]);
            }
#pragma unroll
        for (int j = 0; j < 4; j++) {
            int d = j * 16 + lr;                  // d&3==lr&3, (d>>2)&3==lr>>2
            gl_lds16(vg + (size_t)d * M_ROWS + s0 + w * 32 + ((blk ^ rs) * 8),
                     &vsm[p][w][d * 32 + blk * 8]);
        }
    };

    // ---- prologue: Q tile -> ksm buf 1 (consumed into registers before any
    // staging lands there again)
    {
        const u16* qg = Q + (size_t)(b * S_SEQ + q0) * E_DIM + h * 64;
#pragma unroll
        for (int kb = 0; kb < 2; kb++)
#pragma unroll
            for (int j = 0; j < 2; j++) {
                int row = w * 32 + j * 16 + lr;
                gl_lds16(qg + (size_t)row * E_DIM + kb * 32 + ((blk ^ rs) * 8),
                         &ksm[1][kb][row * 32 + blk * 8]);
            }
    }
    __syncthreads();

    bf16x8 qa[2][2];
#pragma unroll
    for (int mt = 0; mt < 2; mt++)
#pragma unroll
        for (int kb = 0; kb < 2; kb++) {
            int row = w * 32 + mt * 16 + n;       // (row>>2)&3 == n>>2
            qa[mt][kb] = *(const bf16x8*)&ksm[1][kb][row * 32 + ((qd ^ ns) * 8)];
        }

    // issue tile-0 staging into buf 0 (disjoint from ksm[1]; no barrier needed)
    stageKV(0, 0);

    f32x4 acc_o[2][4];
    float lsum[2] = {0.f, 0.f};
#pragma unroll
    for (int mt = 0; mt < 2; mt++)
#pragma unroll
        for (int ntd = 0; ntd < 4; ntd++) acc_o[mt][ntd] = (f32x4){0.f, 0.f, 0.f, 0.f};

    int p = 0;
    for (int s0 = 0; s0 < S_SEQ; s0 += 128) {
        // drains tile-t staging (issued one compute-phase ago) + guarantees all
        // waves are done reading buf p^1 (incl. the prologue qa reads at t=0)
        __syncthreads();
        if (s0 + 128 < S_SEQ) stageKV(p ^ 1, s0 + 128);

        // ---- S^T = K Q^T : lane holds t = mt*16+n, s = nt*16 + qd*4 + r
        f32x4 sacc[2][8];
#pragma unroll
        for (int mt = 0; mt < 2; mt++)
#pragma unroll
            for (int nt = 0; nt < 8; nt++) sacc[mt][nt] = (f32x4){0.f, 0.f, 0.f, 0.f};
#pragma unroll
        for (int nt = 0; nt < 8; nt++) {
            int rowk = nt * 16 + n;               // (rowk>>2)&3 == n>>2
#pragma unroll
            for (int kb = 0; kb < 2; kb++) {
                bf16x8 kf = *(const bf16x8*)&ksm[p][kb][rowk * 32 + ((qd ^ ns) * 8)];
                sacc[0][nt] = MFMA32(kf, qa[0][kb], sacc[0][nt]);
                sacc[1][nt] = MFMA32(kf, qa[1][kb], sacc[1][nt]);
            }
        }

        // ---- max-free exp2 softmax + pack P into A-frags (registers)
        bf16x4 pa[2][8];
#pragma unroll
        for (int mt = 0; mt < 2; mt++) {
            float ls = 0.f;
#pragma unroll
            for (int nt = 0; nt < 8; nt++) {
#pragma unroll
                for (int r = 0; r < 4; r++) {
                    float pv = exp2f(sacc[mt][nt][r]);
                    sacc[mt][nt][r] = pv;
                    ls += pv;
                }
                pa[mt][nt] = pack4(sacc[mt][nt]);
            }
            lsum[mt] += ls;
        }

#if HAVE_MFMA16
        // ---- O += P V via 16x16x16 (P A-frags direct from registers)
#pragma unroll
        for (int kk = 0; kk < 8; kk++) {
            int c = kk >> 1;
            int lblk = (kk & 1) * 2 + (qd >> 1);
#pragma unroll
            for (int ntd = 0; ntd < 4; ntd++) {
                int d = ntd * 16 + n;             // (d>>2)&3 == n>>2
                bf16x4 bv = *(const bf16x4*)
                    &vsm[p][c][d * 32 + ((lblk ^ ns) * 8) + (qd & 1) * 4];
                acc_o[0][ntd] = MFMA16(pa[0][kk], bv, acc_o[0][ntd]);
                acc_o[1][ntd] = MFMA16(pa[1][kk], bv, acc_o[1][ntd]);
            }
        }
#else
        // ---- fallback: packed-b64 psm round-trip, K=32 PV
#pragma unroll
        for (int mt = 0; mt < 2; mt++)
#pragma unroll
            for (int nt = 0; nt < 8; nt++) {
                int t = mt * 16 + n;
                int lb = nt * 2 + (qd >> 1);
                union { bf16x4 v; uint2 u; } pw; pw.v = pa[mt][nt];
                *(uint2*)&psm[w][t * 128 + ((lb ^ n) * 8) + (qd & 1) * 4] = pw.u;
            }
        __syncthreads();
#pragma unroll
        for (int kb = 0; kb < 4; kb++) {
            bf16x8 paf[2];
#pragma unroll
            for (int mt = 0; mt < 2; mt++) {
                int t = mt * 16 + n;
                paf[mt] = *(const bf16x8*)&psm[w][t * 128 + (((kb * 4 + qd) ^ n) * 8)];
            }
#pragma unroll
            for (int ntd = 0; ntd < 4; ntd++) {
                int d = ntd * 16 + n;
                bf16x8 bv = *(const bf16x8*)&vsm[p][kb][d * 32 + ((qd ^ ns) * 8)];
                acc_o[0][ntd] = MFMA32(paf[0], bv, acc_o[0][ntd]);
                acc_o[1][ntd] = MFMA32(paf[1], bv, acc_o[1][ntd]);
            }
        }
#endif
        p ^= 1;
    }

    // ---- epilogue: reduce lsum across quads, divide, scatter
#pragma unroll
    for (int mt = 0; mt < 2; mt++) {
        lsum[mt] += __shfl_xor(lsum[mt], 16);
        lsum[mt] += __shfl_xor(lsum[mt], 32);
    }
#pragma unroll
    for (int mt = 0; mt < 2; mt++)
#pragma unroll
        for (int r = 0; r < 4; r++) {
            float inv = 1.f / __shfl(lsum[mt], qd * 4 + r);
            int grow = b * S_SEQ + q0 + w * 32 + mt * 16 + qd * 4 + r;
#pragma unroll
            for (int ntd = 0; ntd < 4; ntd++) {
                int gcol = h * D_HEAD + ntd * 16 + n;
                O[(size_t)grow * E_DIM + gcol] = f2bf(acc_o[mt][ntd][r] * inv);
            }
        }
}

extern "C" void kernel_launch(void* const* d_in, const int* in_sizes, int n_in,
                              void* d_out, int out_size, void* d_ws, size_t ws_size,
                              hipStream_t stream) {
    const float* query = (const float*)d_in[0];
    const float* key   = (const float*)d_in[1];
    const float* value = (const float*)d_in[2];
    const float* Wq    = (const float*)d_in[3];
    const float* bq    = (const float*)d_in[4];
    const float* Wk    = (const float*)d_in[5];
    const float* bk    = (const float*)d_in[6];
    const float* Wv    = (const float*)d_in[7];
    const float* bv    = (const float*)d_in[8];
    const float* Wo    = (const float*)d_in[9];
    const float* bo    = (const float*)d_in[10];
    float* out = (float*)d_out;

    const int M = M_ROWS;

    // ws plan (13.0 MB, within proven-safe 13.25 MB):
    //   q_bf [M][E] 8MB (attn out aliases) | k_bf .5 | vt_bf .5
    //   wq_bf [E][E] 2MB | wo_bf [E][E] 2MB
    u16* q_bf  = (u16*)d_ws;
    u16* k_bf  = q_bf + (size_t)M * E_DIM;
    u16* vt_bf = k_bf + (size_t)M * D_HEAD;
    u16* wq_bf = vt_bf + (size_t)M * D_HEAD;
    u16* wo_bf = wq_bf + (size_t)E_DIM * E_DIM;

    // query-bf16 scratch lives in d_out (16 MB fp32); consumed by the Q-proj
    // GEMM before the O-proj GEMM writes out.
    u16* qc_bf = (u16*)d_out;

    dim3 blk(256);
    // D^-0.5 * log2(e): softmax uses exp2
    const float scaling = 0.125f * 1.44269504088896f;

    // fused prep: kv_proj (blocks 0..127) + casts (blocks 128..3199)
    prep_kernel<<<dim3(3200), blk, 0, stream>>>(
        query, Wq, Wo, qc_bf, wq_bf, wo_bf,
        key, value, Wk, Wv, bk, bv, k_bf, vt_bf, M, E_DIM);

    // Q projection: both operands bf16, full gl_lds16 staging. Output bf16,
    // pre-scaled by D^-0.5*log2(e).
    gemm_bf16_kernel<true><<<dim3(E_DIM / 64, M / 128), blk, 0, stream>>>(
        qc_bf, wq_bf, bq, q_bf, M, E_DIM, E_DIM, scaling);

    // attn: QBLK=128 -> 512 blocks = 2 blocks/CU, double-buffered K/V
    mqa_attn_mfma_kernel<<<dim3(B_BATCH * H_HEADS * (S_SEQ / 128)), blk, 0, stream>>>(
        q_bf, k_bf, vt_bf, q_bf);

    // O projection: output fp32 into d_out.
    gemm_bf16_kernel<false><<<dim3(E_DIM / 64, M / 128), blk, 0, stream>>>(
        q_bf, wo_bf, bo, out, M, E_DIM, E_DIM, 1.0f);
}

// Round 7
// 235.539 us; speedup vs baseline: 1.0605x; 1.0605x over previous
//
#include <hip/hip_runtime.h>

// MultiQueryAttention: B=2, S=2048, E=1024, H=16, D=64. fp32 I/O.
#define E_DIM  1024
#define H_HEADS 16
#define D_HEAD  64
#define B_BATCH 2
#define S_SEQ  2048
#define M_ROWS (B_BATCH * S_SEQ)   // 4096

typedef unsigned short u16;
typedef unsigned int   u32;
typedef __attribute__((ext_vector_type(8))) short bf16x8;
typedef __attribute__((ext_vector_type(4))) short bf16x4;
typedef __attribute__((ext_vector_type(4))) float f32x4;

#define MFMA32(a, b, c) __builtin_amdgcn_mfma_f32_16x16x32_bf16(a, b, c, 0, 0, 0)

#if __has_builtin(__builtin_amdgcn_mfma_f32_16x16x16bf16_1k)
#define HAVE_MFMA16 1
#define MFMA16(a, b, c) __builtin_amdgcn_mfma_f32_16x16x16bf16_1k(a, b, c, 0, 0, 0)
#else
#define HAVE_MFMA16 0
#endif

__device__ __forceinline__ u16 f2bf(float f) {
    union { float f; u32 i; } x; x.f = f;
    u32 r = x.i + 0x7fffu + ((x.i >> 16) & 1u);   // RNE (finite inputs)
    return (u16)(r >> 16);
}

#if __has_builtin(__builtin_amdgcn_cvt_pk_bf16_f32)
typedef __attribute__((ext_vector_type(2))) __bf16 bfp2;
__device__ __forceinline__ u32 pk2(float a, float b) {
    bfp2 t = __builtin_amdgcn_cvt_pk_bf16_f32(a, b);
    union { bfp2 v; u32 u; } c; c.v = t; return c.u;
}
#else
__device__ __forceinline__ u32 pk2(float a, float b) {
    return (u32)f2bf(a) | ((u32)f2bf(b) << 16);
}
#endif

__device__ __forceinline__ bf16x8 cvt8(const float4& a, const float4& b) {
    union { u32 u[4]; bf16x8 v; } t;
    t.u[0] = pk2(a.x, a.y); t.u[1] = pk2(a.z, a.w);
    t.u[2] = pk2(b.x, b.y); t.u[3] = pk2(b.z, b.w);
    return t.v;
}
__device__ __forceinline__ bf16x4 pack4(const f32x4& v) {
    union { u32 u[2]; bf16x4 w; } t;
    t.u[0] = pk2(v[0], v[1]); t.u[1] = pk2(v[2], v[3]);
    return t.w;
}

// async global->LDS, 16B/lane. LDS dest must be wave-uniform base + lane*16B.
__device__ __forceinline__ void gl_lds16(const u16* g, u16* l) {
    __builtin_amdgcn_global_load_lds(
        (const __attribute__((address_space(1))) u32*)g,
        (__attribute__((address_space(3))) u32*)l, 16, 0, 0);
}

// ---------------------------------------------------------------------------
// Fused prep: K/V projection (128 blocks, FIRST so they start earliest) +
// fp32->bf16 casts of query/Wq/Wo (3072 blocks). Frozen from round 5.
// ---------------------------------------------------------------------------
__global__ __launch_bounds__(256) void prep_kernel(
    const float* __restrict__ query, const float* __restrict__ Wq,
    const float* __restrict__ Wo,
    u16* __restrict__ qc, u16* __restrict__ wq_bf, u16* __restrict__ wo_bf,
    const float* __restrict__ key, const float* __restrict__ value,
    const float* __restrict__ Wk, const float* __restrict__ Wv,
    const float* __restrict__ bk, const float* __restrict__ bv,
    u16* __restrict__ Kout, u16* __restrict__ VTout, int M, int K)
{
    __shared__ u16 Asm[2][64 * 32];
    __shared__ u16 Bsm[2][64 * 32];

    const int bid = blockIdx.x;
    const int tid = threadIdx.x;

    if (bid >= 128) {
        // ---- cast branch: 3072 blocks, 2048 elems each
        const int cbid = bid - 128;
        const float* src; u16* dst; size_t base;
        if (cbid < 2048)      { src = query; dst = qc;    base = (size_t)cbid * 2048; }
        else if (cbid < 2560) { src = Wq;    dst = wq_bf; base = (size_t)(cbid - 2048) * 2048; }
        else                  { src = Wo;    dst = wo_bf; base = (size_t)(cbid - 2560) * 2048; }
        const size_t i = base + (size_t)tid * 8;
        float4 a = ((const float4*)(src + i))[0];
        float4 b = ((const float4*)(src + i))[1];
        *(bf16x8*)(dst + i) = cvt8(a, b);
        return;
    }

    // ---- kv_proj branch: blocks 0..127 (64 m-tiles x {K,V})
    const bool vproj = (bid >= 64);
    const float* A    = vproj ? value : key;
    const float* W    = vproj ? Wv : Wk;
    const float* bias = vproj ? bv : bk;

    const int w  = tid >> 6;
    const int ln = tid & 63;
    const int n  = ln & 15;
    const int qd = ln >> 4;
    const int wm = (w & 1) * 32;
    const int wn = (w >> 1) * 32;
    const int m0 = (bid & 63) * 64;

    const int srow = tid >> 2;
    const int scol = (tid & 3) * 8;

    f32x4 acc[2][2];
#pragma unroll
    for (int mt = 0; mt < 2; mt++)
#pragma unroll
        for (int nt = 0; nt < 2; nt++) acc[mt][nt] = (f32x4){0.f, 0.f, 0.f, 0.f};

    float4 a0, a1, w0, w1;
    auto loadT = [&](int k0) {
        const float* pa = A + (size_t)(m0 + srow) * K + k0 + scol;
        const float* pw = W + (size_t)srow * K + k0 + scol;
        a0 = ((const float4*)pa)[0]; a1 = ((const float4*)pa)[1];
        w0 = ((const float4*)pw)[0]; w1 = ((const float4*)pw)[1];
    };

    const int nk = K / 32;                 // 32 K-steps
    loadT(0);
    *(bf16x8*)&Asm[0][srow * 32 + scol] = cvt8(a0, a1);
    *(bf16x8*)&Bsm[0][srow * 32 + scol] = cvt8(w0, w1);

    for (int t = 0; t < nk; ++t) {
        if (t + 1 < nk) loadT((t + 1) * 32);   // global loads in flight
        __syncthreads();                        // buf[t&1] writes visible

        bf16x8 af[2], bfr[2];
#pragma unroll
        for (int t2 = 0; t2 < 2; t2++) {
            af[t2]  = *(const bf16x8*)&Asm[t & 1][(wm + t2 * 16 + n) * 32 + qd * 8];
            bfr[t2] = *(const bf16x8*)&Bsm[t & 1][(wn + t2 * 16 + n) * 32 + qd * 8];
        }
#pragma unroll
        for (int mt = 0; mt < 2; mt++)
#pragma unroll
            for (int nt = 0; nt < 2; nt++)
                acc[mt][nt] = MFMA32(af[mt], bfr[nt], acc[mt][nt]);

        if (t + 1 < nk) {
            *(bf16x8*)&Asm[(t + 1) & 1][srow * 32 + scol] = cvt8(a0, a1);
            *(bf16x8*)&Bsm[(t + 1) & 1][srow * 32 + scol] = cvt8(w0, w1);
        }
    }

    if (!vproj) {
#pragma unroll
        for (int mt = 0; mt < 2; mt++)
#pragma unroll
            for (int r = 0; r < 4; r++) {
                const int row = m0 + wm + mt * 16 + qd * 4 + r;
#pragma unroll
                for (int nt = 0; nt < 2; nt++) {
                    const int col = wn + nt * 16 + n;
                    Kout[(size_t)row * 64 + col] = f2bf(acc[mt][nt][r] + bias[col]);
                }
            }
    } else {
#pragma unroll
        for (int mt = 0; mt < 2; mt++)
#pragma unroll
            for (int nt = 0; nt < 2; nt++) {
                const int col = wn + nt * 16 + n;
                const int row0 = m0 + wm + mt * 16 + qd * 4;
                float b4 = bias[col];
                ushort4 pk;
                pk.x = f2bf(acc[mt][nt][0] + b4);
                pk.y = f2bf(acc[mt][nt][1] + b4);
                pk.z = f2bf(acc[mt][nt][2] + b4);
                pk.w = f2bf(acc[mt][nt][3] + b4);
                *(ushort4*)&VTout[(size_t)col * M + row0] = pk;
            }
    }
}

// ---------------------------------------------------------------------------
// MFMA GEMM (O-projection only now): C = (A @ W^T)*scale + bias*scale.
// Frozen round-6 structure (counted vmcnt, 3-buf) — measured ≡ drain-0.
// ---------------------------------------------------------------------------
template<bool OUT_BF16>
__global__ __launch_bounds__(256, 2) void gemm_bf16_kernel(
    const u16* __restrict__ A, const u16* __restrict__ W,
    const float* __restrict__ bias, void* __restrict__ Cv,
    int M, int N, int K, float scale)
{
    __shared__ u16 Asm[3][2][128 * 32];   // [buf][k-half][row*32+c]  48 KB
    __shared__ u16 Bsm[3][2][64 * 32];    //                          24 KB

    const int tid = threadIdx.x;          // 0..255
    const int w  = tid >> 6;              // 0..3
    const int ln = tid & 63;
    const int n  = ln & 15;
    const int qd = ln >> 4;
    const int ns = (n & 3) ^ (n >> 2);    // read-side swizzle term
    const int wm = (w & 1) * 64;
    const int wn = (w >> 1) * 32;

    const int m0 = blockIdx.y * 128;
    const int n0 = blockIdx.x * 64;

    const int srow = tid >> 2;            // 0..63
    const int sblk = tid & 3;
    const int sc   = ((sblk ^ (srow & 3) ^ ((srow >> 2) & 3)) * 8);

    f32x4 acc[4][2];
#pragma unroll
    for (int mt = 0; mt < 4; mt++)
#pragma unroll
        for (int nt = 0; nt < 2; nt++) acc[mt][nt] = (f32x4){0.f, 0.f, 0.f, 0.f};

    auto stage = [&](int p, int k0) {     // 6 gl_lds16 per thread
#pragma unroll
        for (int kb = 0; kb < 2; kb++)
#pragma unroll
            for (int g = 0; g < 2; g++) {
                const int row = g * 64 + srow;
                gl_lds16(A + (size_t)(m0 + row) * K + k0 + kb * 32 + sc,
                         &Asm[p][kb][row * 32 + sblk * 8]);
            }
#pragma unroll
        for (int kb = 0; kb < 2; kb++)
            gl_lds16(W + (size_t)(n0 + srow) * K + k0 + kb * 32 + sc,
                     &Bsm[p][kb][srow * 32 + sblk * 8]);
    };
    auto compute = [&](int p) {
        bf16x8 af[4][2], bfr[2][2];
#pragma unroll
        for (int kb = 0; kb < 2; kb++) {
#pragma unroll
            for (int mt = 0; mt < 4; mt++) {
                const int r = wm + mt * 16 + n;
                af[mt][kb] = *(const bf16x8*)&Asm[p][kb][r * 32 + ((qd ^ ns) * 8)];
            }
#pragma unroll
            for (int nt = 0; nt < 2; nt++) {
                const int r = wn + nt * 16 + n;
                bfr[nt][kb] = *(const bf16x8*)&Bsm[p][kb][r * 32 + ((qd ^ ns) * 8)];
            }
        }
#pragma unroll
        for (int kb = 0; kb < 2; kb++)
#pragma unroll
            for (int mt = 0; mt < 4; mt++)
#pragma unroll
                for (int nt = 0; nt < 2; nt++)
                    acc[mt][nt] = MFMA32(af[mt][kb], bfr[nt][kb], acc[mt][nt]);
    };

    const int nt_tiles = K / 64;          // 16
    stage(0, 0);
    stage(1, 64);

    int pc = 0, ps = 2;
    for (int t = 0; t + 2 < nt_tiles; ++t) {
        asm volatile("s_waitcnt vmcnt(6)" ::: "memory");
        __builtin_amdgcn_s_barrier();
        __builtin_amdgcn_sched_barrier(0);
        stage(ps, (t + 2) * 64);
        compute(pc);
        pc = (pc == 2) ? 0 : pc + 1;
        ps = (ps == 2) ? 0 : ps + 1;
    }
    asm volatile("s_waitcnt vmcnt(6)" ::: "memory");
    __builtin_amdgcn_s_barrier();
    __builtin_amdgcn_sched_barrier(0);
    compute(pc);
    pc = (pc == 2) ? 0 : pc + 1;
    asm volatile("s_waitcnt vmcnt(0)" ::: "memory");
    __builtin_amdgcn_s_barrier();
    __builtin_amdgcn_sched_barrier(0);
    compute(pc);

    float bb[2];
#pragma unroll
    for (int nt = 0; nt < 2; nt++) bb[nt] = bias[n0 + wn + nt * 16 + n] * scale;

#pragma unroll
    for (int mt = 0; mt < 4; mt++)
#pragma unroll
        for (int r = 0; r < 4; r++) {
            const int row = m0 + wm + mt * 16 + qd * 4 + r;
#pragma unroll
            for (int nt = 0; nt < 2; nt++) {
                const int col = n0 + wn + nt * 16 + n;
                float v = acc[mt][nt][r] * scale + bb[nt];
                if (OUT_BF16) ((u16*)Cv)[(size_t)row * N + col] = f2bf(v);
                else        ((float*)Cv)[(size_t)row * N + col] = v;
            }
        }
}

// ---------------------------------------------------------------------------
// FUSED Q-projection + MFMA flash MQA attention (this round's change).
// Phase 1: Q[128x64] = (qc[128x1024] @ Wq_h[64x1024]^T)*scale + bq*scale,
//   computed per-block with the proven GEMM frag/swizzle algebra (wave tile
//   32x64, dbuf single-barrier loop, gl_lds16 staging), packed bf16 into a
//   spare LDS region (QSM), read back as qa B-frags. Replaces the standalone
//   Q-GEMM dispatch + its 8MB global round-trip + one launch gap.
// Phase 2: round-5 attn loop verbatim (dbuf K/V, 3-bit XOR swizzle,
//   S^T = K Q^T, max-free exp2 softmax, PV via MFMA16 from registers).
// LDS: one flat 64KB array, time-shared:
//   phase1: buf b at [b*12288): A [2kb][128*32], B at +8192 [2kb][64*32]
//   Qpack:  QSM at [24576) = [2kb][128*32]  (untouched by phase-1 bufs)
//   phase2: KSM(p,kb)=[(p*2+kb)*4096), VSM(p,c)=[16384+(p*4+c)*2048)
//   (VSM(1,*) overlaps QSM — safe: qa is in registers before any stageKV(1)
//    lands, and iter-0's __syncthreads drains the qa ds_reads first.)
// Grid 512 = 2 blocks/CU. O = q_bf (pure output now; no aliasing).
// ---------------------------------------------------------------------------
__global__ __launch_bounds__(256, 2) void mqa_attn_fused_kernel(
    const u16* __restrict__ QC, const u16* __restrict__ WQ,
    const float* __restrict__ bq,
    const u16* __restrict__ Kt, const u16* __restrict__ VT,
    u16* __restrict__ O, float scaling)
{
    __shared__ u16 lds[32768];            // 64 KB
#if !HAVE_MFMA16
    __shared__ u16 psm[4][32 * 128];
#endif

    const int tid = threadIdx.x;
    const int w   = tid >> 6;
    const int ln  = tid & 63;
    const int n   = ln & 15;
    const int qd  = ln >> 4;
    const int lr  = ln >> 2;           // 0..15
    const int blk = ln & 3;
    const int ns  = (n & 3) ^ (n >> 2);        // read-side swizzle term
    const int rs  = (lr & 3) ^ (lr >> 2);      // stage-side swizzle term (KV)

    const int bid = blockIdx.x;
    const int qb = bid & 15;
    const int h  = (bid >> 4) & (H_HEADS - 1);
    const int b  = bid >> 8;
    const int q0 = qb * 128;

    // ---------------- phase 1: Q-projection ----------------
    const u16* ag = QC + (size_t)(b * S_SEQ + q0) * E_DIM;   // 128 q rows
    const u16* wg = WQ + (size_t)(h * 64) * E_DIM;           // 64 Wq rows

    const int srow = tid >> 2;            // 0..63
    const int sblk = tid & 3;
    const int sc   = ((sblk ^ (srow & 3) ^ ((srow >> 2) & 3)) * 8);

    auto stageP1 = [&](int buf, int k0) {  // 6 gl_lds16 per thread
        u16* pa = lds + buf * 12288;
        u16* pb = pa + 8192;
#pragma unroll
        for (int kb = 0; kb < 2; kb++)
#pragma unroll
            for (int g = 0; g < 2; g++) {
                const int row = g * 64 + srow;   // swizzle bits of row == srow's
                gl_lds16(ag + (size_t)row * E_DIM + k0 + kb * 32 + sc,
                         pa + kb * 4096 + row * 32 + sblk * 8);
            }
#pragma unroll
        for (int kb = 0; kb < 2; kb++)
            gl_lds16(wg + (size_t)srow * E_DIM + k0 + kb * 32 + sc,
                     pb + kb * 2048 + srow * 32 + sblk * 8);
    };

    float bqv[4];
#pragma unroll
    for (int nt = 0; nt < 4; nt++) bqv[nt] = bq[h * 64 + nt * 16 + n] * scaling;

    f32x4 qacc[2][4];                     // wave tile 32(M) x 64(N)
#pragma unroll
    for (int mt = 0; mt < 2; mt++)
#pragma unroll
        for (int nt = 0; nt < 4; nt++) qacc[mt][nt] = (f32x4){0.f, 0.f, 0.f, 0.f};

    stageP1(0, 0);
    for (int t = 0; t < 16; ++t) {
        __syncthreads();                          // stage(t) drained
        if (t + 1 < 16) stageP1((t + 1) & 1, (t + 1) * 64);
        const u16* pa = lds + (t & 1) * 12288;
        const u16* pb = pa + 8192;
        bf16x8 af[2][2], bfr[4][2];
#pragma unroll
        for (int kb = 0; kb < 2; kb++) {
#pragma unroll
            for (int mt = 0; mt < 2; mt++) {
                const int r = w * 32 + mt * 16 + n;
                af[mt][kb] = *(const bf16x8*)&pa[kb * 4096 + r * 32 + ((qd ^ ns) * 8)];
            }
#pragma unroll
            for (int nt = 0; nt < 4; nt++) {
                const int r = nt * 16 + n;
                bfr[nt][kb] = *(const bf16x8*)&pb[kb * 2048 + r * 32 + ((qd ^ ns) * 8)];
            }
        }
#pragma unroll
        for (int kb = 0; kb < 2; kb++)
#pragma unroll
            for (int mt = 0; mt < 2; mt++)
#pragma unroll
                for (int nt = 0; nt < 4; nt++)
                    qacc[mt][nt] = MFMA32(af[mt][kb], bfr[nt][kb], qacc[mt][nt]);
    }

    // pack Q (scale+bias) into QSM in the swizzled [kb][row*32] layout.
    // Wave w computed exactly rows w*32..w*32+31 — the rows its qa needs.
    {
        u16* qsm = lds + 24576;
#pragma unroll
        for (int mt = 0; mt < 2; mt++)
#pragma unroll
            for (int r = 0; r < 4; r++) {
                const int row = w * 32 + mt * 16 + qd * 4 + r;
                const int rsw = (row & 3) ^ ((row >> 2) & 3);
#pragma unroll
                for (int nt = 0; nt < 4; nt++) {
                    const int col = nt * 16 + n;      // d 0..63
                    float v = qacc[mt][nt][r] * scaling + bqv[nt];
                    const int kb = col >> 5, c = col & 31;
                    qsm[kb * 4096 + row * 32 + (((c >> 3) ^ rsw) * 8) + (c & 7)] = f2bf(v);
                }
            }
    }
    __syncthreads();                       // Q writes visible (lgkm drained)

    bf16x8 qa[2][2];
#pragma unroll
    for (int mt = 0; mt < 2; mt++)
#pragma unroll
        for (int kb = 0; kb < 2; kb++) {
            const int row = w * 32 + mt * 16 + n;
            qa[mt][kb] = *(const bf16x8*)&lds[24576 + kb * 4096 + row * 32 + ((qd ^ ns) * 8)];
        }

    // ---------------- phase 2: flash attention ----------------
    const u16* kg = Kt + (size_t)b * S_SEQ * 64;
    const u16* vg = VT + (size_t)b * S_SEQ;

    auto KSM = [&](int p, int kb) -> u16* { return lds + ((p * 2 + kb) * 4096); };
    auto VSM = [&](int p, int c)  -> u16* { return lds + 16384 + ((p * 4 + c) * 2048); };

    auto stageKV = [&](int p, int s0) {
#pragma unroll
        for (int kb = 0; kb < 2; kb++)
#pragma unroll
            for (int j = 0; j < 2; j++) {
                const int row = w * 32 + j * 16 + lr;
                gl_lds16(kg + (size_t)(s0 + row) * 64 + kb * 32 + ((blk ^ rs) * 8),
                         KSM(p, kb) + row * 32 + blk * 8);
            }
#pragma unroll
        for (int j = 0; j < 4; j++) {
            const int d = j * 16 + lr;
            gl_lds16(vg + (size_t)d * M_ROWS + s0 + w * 32 + ((blk ^ rs) * 8),
                     VSM(p, w) + d * 32 + blk * 8);
        }
    };

    // qa ds_reads drain at the iter-0 __syncthreads, before stageKV(1) can
    // overwrite the QSM/VSM(1) region.
    stageKV(0, 0);

    f32x4 acc_o[2][4];
    float lsum[2] = {0.f, 0.f};
#pragma unroll
    for (int mt = 0; mt < 2; mt++)
#pragma unroll
        for (int ntd = 0; ntd < 4; ntd++) acc_o[mt][ntd] = (f32x4){0.f, 0.f, 0.f, 0.f};

    int p = 0;
    for (int s0 = 0; s0 < S_SEQ; s0 += 128) {
        __syncthreads();                   // stage(t) drained; prev readers done
        if (s0 + 128 < S_SEQ) stageKV(p ^ 1, s0 + 128);

        // ---- S^T = K Q^T : lane holds t = mt*16+n, s = nt*16 + qd*4 + r
        f32x4 sacc[2][8];
#pragma unroll
        for (int mt = 0; mt < 2; mt++)
#pragma unroll
            for (int nt = 0; nt < 8; nt++) sacc[mt][nt] = (f32x4){0.f, 0.f, 0.f, 0.f};
#pragma unroll
        for (int nt = 0; nt < 8; nt++) {
            const int rowk = nt * 16 + n;
#pragma unroll
            for (int kb = 0; kb < 2; kb++) {
                bf16x8 kf = *(const bf16x8*)&KSM(p, kb)[rowk * 32 + ((qd ^ ns) * 8)];
                sacc[0][nt] = MFMA32(kf, qa[0][kb], sacc[0][nt]);
                sacc[1][nt] = MFMA32(kf, qa[1][kb], sacc[1][nt]);
            }
        }

        // ---- max-free exp2 softmax + pack P into A-frags (registers)
        bf16x4 pa[2][8];
#pragma unroll
        for (int mt = 0; mt < 2; mt++) {
            float ls = 0.f;
#pragma unroll
            for (int nt = 0; nt < 8; nt++) {
#pragma unroll
                for (int r = 0; r < 4; r++) {
                    float pv = exp2f(sacc[mt][nt][r]);
                    sacc[mt][nt][r] = pv;
                    ls += pv;
                }
                pa[mt][nt] = pack4(sacc[mt][nt]);
            }
            lsum[mt] += ls;
        }

#if HAVE_MFMA16
        // ---- O += P V via 16x16x16 (P A-frags direct from registers)
#pragma unroll
        for (int kk = 0; kk < 8; kk++) {
            const int c = kk >> 1;
            const int lblk = (kk & 1) * 2 + (qd >> 1);
#pragma unroll
            for (int ntd = 0; ntd < 4; ntd++) {
                const int d = ntd * 16 + n;
                bf16x4 bv = *(const bf16x4*)
                    &VSM(p, c)[d * 32 + ((lblk ^ ns) * 8) + (qd & 1) * 4];
                acc_o[0][ntd] = MFMA16(pa[0][kk], bv, acc_o[0][ntd]);
                acc_o[1][ntd] = MFMA16(pa[1][kk], bv, acc_o[1][ntd]);
            }
        }
#else
        // ---- fallback: packed-b64 psm round-trip, K=32 PV
#pragma unroll
        for (int mt = 0; mt < 2; mt++)
#pragma unroll
            for (int nt = 0; nt < 8; nt++) {
                const int t = mt * 16 + n;
                const int lb = nt * 2 + (qd >> 1);
                union { bf16x4 v; uint2 u; } pw; pw.v = pa[mt][nt];
                *(uint2*)&psm[w][t * 128 + ((lb ^ n) * 8) + (qd & 1) * 4] = pw.u;
            }
        __syncthreads();
#pragma unroll
        for (int kb = 0; kb < 4; kb++) {
            bf16x8 paf[2];
#pragma unroll
            for (int mt = 0; mt < 2; mt++) {
                const int t = mt * 16 + n;
                paf[mt] = *(const bf16x8*)&psm[w][t * 128 + (((kb * 4 + qd) ^ n) * 8)];
            }
#pragma unroll
            for (int ntd = 0; ntd < 4; ntd++) {
                const int d = ntd * 16 + n;
                bf16x8 bv = *(const bf16x8*)&VSM(p, kb)[d * 32 + ((qd ^ ns) * 8)];
                acc_o[0][ntd] = MFMA32(paf[0], bv, acc_o[0][ntd]);
                acc_o[1][ntd] = MFMA32(paf[1], bv, acc_o[1][ntd]);
            }
        }
#endif
        p ^= 1;
    }

    // ---- epilogue: reduce lsum across quads, divide, scatter
#pragma unroll
    for (int mt = 0; mt < 2; mt++) {
        lsum[mt] += __shfl_xor(lsum[mt], 16);
        lsum[mt] += __shfl_xor(lsum[mt], 32);
    }
#pragma unroll
    for (int mt = 0; mt < 2; mt++)
#pragma unroll
        for (int r = 0; r < 4; r++) {
            float inv = 1.f / __shfl(lsum[mt], qd * 4 + r);
            const int grow = b * S_SEQ + q0 + w * 32 + mt * 16 + qd * 4 + r;
#pragma unroll
            for (int ntd = 0; ntd < 4; ntd++) {
                const int gcol = h * D_HEAD + ntd * 16 + n;
                O[(size_t)grow * E_DIM + gcol] = f2bf(acc_o[mt][ntd][r] * inv);
            }
        }
}

extern "C" void kernel_launch(void* const* d_in, const int* in_sizes, int n_in,
                              void* d_out, int out_size, void* d_ws, size_t ws_size,
                              hipStream_t stream) {
    const float* query = (const float*)d_in[0];
    const float* key   = (const float*)d_in[1];
    const float* value = (const float*)d_in[2];
    const float* Wq    = (const float*)d_in[3];
    const float* bq    = (const float*)d_in[4];
    const float* Wk    = (const float*)d_in[5];
    const float* bk    = (const float*)d_in[6];
    const float* Wv    = (const float*)d_in[7];
    const float* bv    = (const float*)d_in[8];
    const float* Wo    = (const float*)d_in[9];
    const float* bo    = (const float*)d_in[10];
    float* out = (float*)d_out;

    const int M = M_ROWS;

    // ws plan (13.0 MB, within proven-safe 13.25 MB):
    //   q_bf [M][E] 8MB (attn output -> O-proj input) | k_bf .5 | vt_bf .5
    //   wq_bf [E][E] 2MB | wo_bf [E][E] 2MB
    u16* q_bf  = (u16*)d_ws;
    u16* k_bf  = q_bf + (size_t)M * E_DIM;
    u16* vt_bf = k_bf + (size_t)M * D_HEAD;
    u16* wq_bf = vt_bf + (size_t)M * D_HEAD;
    u16* wo_bf = wq_bf + (size_t)E_DIM * E_DIM;

    // query-bf16 scratch lives in d_out (16 MB fp32); consumed by the fused
    // attn kernel before the O-proj GEMM writes out.
    u16* qc_bf = (u16*)d_out;

    dim3 blk(256);
    // D^-0.5 * log2(e): softmax uses exp2
    const float scaling = 0.125f * 1.44269504088896f;

    // fused prep: kv_proj (blocks 0..127) + casts (blocks 128..3199)
    prep_kernel<<<dim3(3200), blk, 0, stream>>>(
        query, Wq, Wo, qc_bf, wq_bf, wo_bf,
        key, value, Wk, Wv, bk, bv, k_bf, vt_bf, M, E_DIM);

    // fused Q-proj + attention: 512 blocks = 2 blocks/CU
    mqa_attn_fused_kernel<<<dim3(512), blk, 0, stream>>>(
        qc_bf, wq_bf, bq, k_bf, vt_bf, q_bf, scaling);

    // O projection: output fp32 into d_out.
    gemm_bf16_kernel<false><<<dim3(E_DIM / 64, M / 128), blk, 0, stream>>>(
        q_bf, wo_bf, bo, out, M, E_DIM, E_DIM, 1.0f);
}